// Round 9
// baseline (153.423 us; speedup 1.0000x reference)
//
#include <hip/hip_runtime.h>
#include <math.h>

#define BB 4
#define LL 1024
#define EE 512
#define HH 8
#define DD 64
#define MAXREL 512

typedef unsigned short u16;
typedef __attribute__((ext_vector_type(8))) short bf16x8;
typedef __attribute__((ext_vector_type(4))) float f32x4;

__device__ __forceinline__ u16 f2bf(float f) {
    unsigned int u = __float_as_uint(f);
    unsigned int r = (u + 0x7FFFu + ((u >> 16) & 1u)) >> 16;
    return (u16)r;
}
__device__ __forceinline__ float bf2f(u16 b) {
    return __uint_as_float(((unsigned int)b) << 16);
}
__device__ __forceinline__ bf16x8 ldf8_bf(const float* p) {
    const float4 a = *(const float4*)(p);
    const float4 b = *(const float4*)(p + 4);
    bf16x8 r;
    r[0] = (short)f2bf(a.x); r[1] = (short)f2bf(a.y);
    r[2] = (short)f2bf(a.z); r[3] = (short)f2bf(a.w);
    r[4] = (short)f2bf(b.x); r[5] = (short)f2bf(b.y);
    r[6] = (short)f2bf(b.z); r[7] = (short)f2bf(b.w);
    return r;
}

#define MF(A, B, C) __builtin_amdgcn_mfma_f32_16x16x32_bf16((A), (B), (C), 0, 0, 0)
// exp(x/8) = exp2(x * log2(e)/8)
#define EXPSC 0.1803368801111244f

// ---------------- projection via MFMA ----------------
__global__ __launch_bounds__(256) void proj_mfma_kernel(
    const float* __restrict__ q_in, const float* __restrict__ k_in, const float* __restrict__ v_in,
    const float* __restrict__ Wq, const float* __restrict__ bq,
    const float* __restrict__ Wk, const float* __restrict__ bk,
    const float* __restrict__ Wv, const float* __restrict__ bv,
    u16* __restrict__ qb, u16* __restrict__ kb, u16* __restrict__ vtb)
{
    int bh = blockIdx.x; int b = bh >> 3; int h = bh & 7;
    int l0 = blockIdx.y * 64;
    int t = threadIdx.x; int w = t >> 6; int lane = t & 63;
    int lg = lane >> 4, lc = lane & 15;
    int lt = l0 + w * 16;

    bf16x8 wq[4][2], wk[4][2], wv[4][2];
    #pragma unroll
    for (int dt = 0; dt < 4; ++dt)
        #pragma unroll
        for (int kc = 0; kc < 2; ++kc) {
            int d = dt * 16 + lc, ko = kc * 32 + lg * 8;
            wq[dt][kc] = ldf8_bf(Wq + d * DD + ko);
            wk[dt][kc] = ldf8_bf(Wk + d * DD + ko);
            wv[dt][kc] = ldf8_bf(Wv + d * DD + ko);
        }
    size_t xrow = ((size_t)b * LL + lt + lc) * EE + h * DD;
    bf16x8 xq[2], xk[2], xv[2];
    #pragma unroll
    for (int kc = 0; kc < 2; ++kc) {
        int ko = kc * 32 + lg * 8;
        xq[kc] = ldf8_bf(q_in + xrow + ko);
        xk[kc] = ldf8_bf(k_in + xrow + ko);
        xv[kc] = ldf8_bf(v_in + xrow + ko);
    }

    f32x4 aq[4] = {}, ak[4] = {}, av[4] = {};
    #pragma unroll
    for (int dt = 0; dt < 4; ++dt) {
        aq[dt] = MF(wq[dt][0], xq[0], aq[dt]);
        aq[dt] = MF(wq[dt][1], xq[1], aq[dt]);
        ak[dt] = MF(wk[dt][0], xk[0], ak[dt]);
        ak[dt] = MF(wk[dt][1], xk[1], ak[dt]);
        av[dt] = MF(xv[0], wv[dt][0], av[dt]);
        av[dt] = MF(xv[1], wv[dt][1], av[dt]);
    }

    #pragma unroll
    for (int dt = 0; dt < 4; ++dt) {
        u16 tq[4], tk[4], tv[4];
        #pragma unroll
        for (int r = 0; r < 4; ++r) {
            int d = dt * 16 + lg * 4 + r;
            tq[r] = f2bf(aq[dt][r] + bq[d]);
            tk[r] = f2bf(ak[dt][r] + bk[d]);
            tv[r] = f2bf(av[dt][r] + bv[dt * 16 + lc]);
        }
        size_t o = ((size_t)bh * LL + lt + lc) * DD + dt * 16 + lg * 4;
        *(uint2*)&qb[o] = *(uint2*)tq;
        *(uint2*)&kb[o] = *(uint2*)tk;
        size_t ov = ((size_t)bh * DD + dt * 16 + lc) * LL + lt + lg * 4;
        *(uint2*)&vtb[ov] = *(uint2*)tv;
    }
}

// ---------------- prep: padded bf16 rel tables + bf16 Wfc ----------------
__global__ __launch_bounds__(256) void prep_kernel(
    const float* __restrict__ relk, const float* __restrict__ relv, const float* __restrict__ Wfc,
    u16* __restrict__ relk_pad, u16* __restrict__ relvt_pad, u16* __restrict__ wfcb)
{
    int idx = blockIdx.x * 256 + threadIdx.x;   // 1024 blocks -> 262144
    if (idx < 2048 * DD) {
        int r = idx >> 6, d = idx & 63;
        int j = r - 512; j = j < 0 ? 0 : (j > 2 * MAXREL ? 2 * MAXREL : j);
        relk_pad[idx] = f2bf(relk[j * DD + d]);
        int dd = idx >> 11, c = idx & 2047;
        int j2 = c - 512; j2 = j2 < 0 ? 0 : (j2 > 2 * MAXREL ? 2 * MAXREL : j2);
        relvt_pad[idx] = f2bf(relv[j2 * DD + dd]);
    }
    if (idx < EE * EE) wfcb[idx] = f2bf(Wfc[idx]);
}

// ---------------- fused attention ----------------
// grid (B*H, L/32), block 256 (4 waves). 2 barriers/chunk. Wave-local P.
// K/V/rel-V: LDS tiles, all stage loads issued at chunk TOP (full-chunk T14 cover).
// rel-K: register B-frags, prefetch distance 2 (two named sets, loop unrolled x2).
__global__ __launch_bounds__(256) void attn_mfma_kernel(
    const u16* __restrict__ qb, const u16* __restrict__ kb, const u16* __restrict__ vtb,
    const int* __restrict__ mask,
    const u16* __restrict__ relk_pad, const u16* __restrict__ relvt_pad,
    u16* __restrict__ attn_out)
{
    __shared__ __align__(16) char smem[48384];
    u16* Ks   = (u16*)(smem);             // [64][72]   9216
    u16* Vts  = (u16*)(smem + 9216);      // [64][72]   9216
    u16* RVts = (u16*)(smem + 18432);     // [64][120] 15360
    float* lred = (float*)(smem + 48128); // [64]
    float* obuf = (float*)smem;           // epilogue reuse [32][68]

    int bh = blockIdx.x, b = bh >> 3, h = bh & 7;
    int q0 = blockIdx.y * 32;
    int t = threadIdx.x, lane = t & 63, w = t >> 6;
    int rw = w & 1, cw = w >> 1;
    int rbase = rw * 16, c0a = cw * 32;
    int lg = lane >> 4, lc = lane & 15;
    int ub = c0a - rbase + 16;            // window base (0,16,32,48)
    size_t bhL = (size_t)bh * LL;
    const u16* kb_bh = kb + bhL * DD;
    const u16* vt_bh = vtb + (size_t)bh * DD * LL;
    const int* mk_b = mask + b * LL;
    u16* Pw  = (u16*)(smem + 33792) + w * 640;   // [16][40] per wave
    u16* Pqw = (u16*)(smem + 38912) + w * 1152;  // [16][72] per wave

    // staging index precompute
    int sr0 = t >> 3, ss0 = (t & 7) * 8;
    int sr1 = sr0 + 32;
    int rv_row = t >> 2, rv_q = (t & 3) * 24;
    const u16* rvg = relvt_pad + (size_t)rv_row * 2048 + rv_q;
    u16* rvl = RVts + rv_row * 120 + rv_q;
    const u16* rk_base = relk_pad + (size_t)(ub + lc) * DD + lg * 8;

    const u16* qrow = qb + (bhL + q0 + rbase + lc) * DD;
    bf16x8 qf0 = *(const bf16x8*)&qrow[lg * 8];
    bf16x8 qf1 = *(const bf16x8*)&qrow[32 + lg * 8];

    // ---- prolog: zero Pqw band + RVts pad; stage chunk 0; prefetch rel-K(0),(1) ----
    #pragma unroll
    for (int i = 0; i < 3; ++i) {
        int u = lane + i * 64;
        if (u < 144) *(uint4*)&Pqw[u * 8] = make_uint4(0, 0, 0, 0);
    }
    if (t < 192) {
        int row = t / 3, j = t - row * 3;
        *(uint4*)&RVts[row * 120 + 96 + j * 8] = make_uint4(0, 0, 0, 0);
    }
    int sb0 = 992 - q0;
    *(uint4*)&Ks[sr0 * 72 + ss0]  = *(const uint4*)&kb_bh[(size_t)sr0 * DD + ss0];
    *(uint4*)&Ks[sr1 * 72 + ss0]  = *(const uint4*)&kb_bh[(size_t)sr1 * DD + ss0];
    *(uint4*)&Vts[sr0 * 72 + ss0] = *(const uint4*)&vt_bh[(size_t)sr0 * LL + ss0];
    *(uint4*)&Vts[sr1 * 72 + ss0] = *(const uint4*)&vt_bh[(size_t)sr1 * LL + ss0];
    *(uint4*)&rvl[0]  = *(const uint4*)&rvg[sb0];
    *(uint4*)&rvl[8]  = *(const uint4*)&rvg[sb0 + 8];
    *(uint4*)&rvl[16] = *(const uint4*)&rvg[sb0 + 16];
    bf16x8 rkA0, rkA1, rkA2, rkA3, rkA4, rkA5;
    bf16x8 rkB0, rkB1, rkB2, rkB3, rkB4, rkB5;
    {
        const u16* rkp = rk_base + (size_t)sb0 * DD;
        rkA0 = *(const bf16x8*)&rkp[0];
        rkA1 = *(const bf16x8*)&rkp[32];
        rkA2 = *(const bf16x8*)&rkp[16 * DD];
        rkA3 = *(const bf16x8*)&rkp[16 * DD + 32];
        rkA4 = *(const bf16x8*)&rkp[32 * DD];
        rkA5 = *(const bf16x8*)&rkp[32 * DD + 32];
        const u16* rkq = rk_base + (size_t)(sb0 + 64) * DD;
        rkB0 = *(const bf16x8*)&rkq[0];
        rkB1 = *(const bf16x8*)&rkq[32];
        rkB2 = *(const bf16x8*)&rkq[16 * DD];
        rkB3 = *(const bf16x8*)&rkq[16 * DD + 32];
        rkB4 = *(const bf16x8*)&rkq[32 * DD];
        rkB5 = *(const bf16x8*)&rkq[32 * DD + 32];
    }
    float mb0 = (mk_b[c0a + lc] != 0) ? 0.f : -1e20f;
    float mb1 = (mk_b[c0a + 16 + lc] != 0) ? 0.f : -1e20f;
    __syncthreads();

    f32x4 oacc[4] = {};
    float lacc[4] = {0.f, 0.f, 0.f, 0.f};
    int delta0 = lc - lg * 4;

#define CHUNK(C, RK0, RK1, RK2, RK3, RK4, RK5) do { \
    int k0 = (C) * 64; \
    int sb_ = k0 - q0 + 992; \
    uint4 rK0, rK1, rV0, rV1, bb0, bb1, bb2; \
    float mbn0 = 0.f, mbn1 = 0.f; \
    if ((C) < 15) { \
        int k0n = k0 + 64; int sbn_ = sb_ + 64; \
        rK0 = *(const uint4*)&kb_bh[(size_t)(k0n + sr0) * DD + ss0]; \
        rK1 = *(const uint4*)&kb_bh[(size_t)(k0n + sr1) * DD + ss0]; \
        rV0 = *(const uint4*)&vt_bh[(size_t)sr0 * LL + k0n + ss0]; \
        rV1 = *(const uint4*)&vt_bh[(size_t)sr1 * LL + k0n + ss0]; \
        bb0 = *(const uint4*)&rvg[sbn_]; \
        bb1 = *(const uint4*)&rvg[sbn_ + 8]; \
        bb2 = *(const uint4*)&rvg[sbn_ + 16]; \
        mbn0 = (mk_b[k0n + c0a + lc] != 0) ? 0.f : -1e20f; \
        mbn1 = (mk_b[k0n + c0a + 16 + lc] != 0) ? 0.f : -1e20f; \
    } \
    __builtin_amdgcn_s_setprio(1); \
    f32x4 s0 = {}, s1 = {}; \
    { \
        const u16* kp0 = &Ks[(c0a + lc) * 72]; \
        const u16* kp1 = &Ks[(c0a + 16 + lc) * 72]; \
        s0 = MF(qf0, *(const bf16x8*)&kp0[lg * 8], s0); \
        s0 = MF(qf1, *(const bf16x8*)&kp0[32 + lg * 8], s0); \
        s1 = MF(qf0, *(const bf16x8*)&kp1[lg * 8], s1); \
        s1 = MF(qf1, *(const bf16x8*)&kp1[32 + lg * 8], s1); \
    } \
    f32x4 g0 = {}, g1 = {}, g2 = {}; \
    g0 = MF(qf0, RK0, g0); g0 = MF(qf1, RK1, g0); \
    g1 = MF(qf0, RK2, g1); g1 = MF(qf1, RK3, g1); \
    g2 = MF(qf0, RK4, g2); g2 = MF(qf1, RK5, g2); \
    __builtin_amdgcn_s_setprio(0); \
    if ((C) < 14) { \
        const u16* rkp_ = rk_base + (size_t)(sb_ + 128) * DD; \
        RK0 = *(const bf16x8*)&rkp_[0]; \
        RK1 = *(const bf16x8*)&rkp_[32]; \
        RK2 = *(const bf16x8*)&rkp_[16 * DD]; \
        RK3 = *(const bf16x8*)&rkp_[16 * DD + 32]; \
        RK4 = *(const bf16x8*)&rkp_[32 * DD]; \
        RK5 = *(const bf16x8*)&rkp_[32 * DD + 32]; \
    } \
    _Pragma("unroll") \
    for (int r = 0; r < 4; ++r) { \
        int d_ = delta0 - r; \
        int src = (lane & 48) | (d_ & 15); \
        float a0 = __shfl(g0[r], src, 64); \
        float a1 = __shfl(g1[r], src, 64); \
        float a2 = __shfl(g2[r], src, 64); \
        float gv0 = (d_ >= 0) ? a1 : a0; \
        float gv1 = (d_ >= 0) ? a2 : a1; \
        float p0 = exp2f((s0[r] + mb0 + gv0) * EXPSC); \
        float p1 = exp2f((s1[r] + mb1 + gv1) * EXPSC); \
        u16 pb0 = f2bf(p0), pb1 = f2bf(p1); \
        lacc[r] += p0 + p1; \
        int row = lg * 4 + r; \
        Pw[row * 40 + lc] = pb0; \
        Pw[row * 40 + 16 + lc] = pb1; \
        Pqw[row * 72 + lc - row + 16] = pb0; \
        Pqw[row * 72 + 32 + lc - row] = pb1; \
    } \
    mb0 = mbn0; mb1 = mbn1; \
    asm volatile("s_waitcnt lgkmcnt(0)" ::: "memory"); \
    __builtin_amdgcn_sched_barrier(0); \
    bf16x8 pa  = *(const bf16x8*)&Pw[lc * 40 + lg * 8]; \
    bf16x8 pq0 = *(const bf16x8*)&Pqw[lc * 72 + lg * 8]; \
    bf16x8 pq1 = *(const bf16x8*)&Pqw[lc * 72 + 32 + lg * 8]; \
    __builtin_amdgcn_s_setprio(1); \
    _Pragma("unroll") \
    for (int dt = 0; dt < 4; ++dt) { \
        const u16* vp = &Vts[(dt * 16 + lc) * 72 + c0a]; \
        const u16* rp = &RVts[(dt * 16 + lc) * 120 + ub]; \
        oacc[dt] = MF(pa,  *(const bf16x8*)&vp[lg * 8], oacc[dt]); \
        oacc[dt] = MF(pq0, *(const bf16x8*)&rp[lg * 8], oacc[dt]); \
        oacc[dt] = MF(pq1, *(const bf16x8*)&rp[32 + lg * 8], oacc[dt]); \
    } \
    __builtin_amdgcn_s_setprio(0); \
    if ((C) < 15) { \
        __syncthreads(); \
        *(uint4*)&Ks[sr0 * 72 + ss0]  = rK0; \
        *(uint4*)&Ks[sr1 * 72 + ss0]  = rK1; \
        *(uint4*)&Vts[sr0 * 72 + ss0] = rV0; \
        *(uint4*)&Vts[sr1 * 72 + ss0] = rV1; \
        *(uint4*)&rvl[0]  = bb0; \
        *(uint4*)&rvl[8]  = bb1; \
        *(uint4*)&rvl[16] = bb2; \
        __syncthreads(); \
    } \
} while (0)

    #pragma unroll 1
    for (int cc = 0; cc < 16; cc += 2) {
        CHUNK(cc,     rkA0, rkA1, rkA2, rkA3, rkA4, rkA5);
        CHUNK(cc + 1, rkB0, rkB1, rkB2, rkB3, rkB4, rkB5);
    }
#undef CHUNK

    // ---- epilogue: row-sum + cw-pair combine ----
    #pragma unroll
    for (int m2 = 1; m2 <= 8; m2 <<= 1) {
        #pragma unroll
        for (int r = 0; r < 4; ++r) lacc[r] += __shfl_xor(lacc[r], m2);
    }
    if (lc == 0) {
        #pragma unroll
        for (int r = 0; r < 4; ++r) lred[cw * 32 + rbase + lg * 4 + r] = lacc[r];
    }
    __syncthreads();
    if (cw == 1) {
        #pragma unroll
        for (int dt = 0; dt < 4; ++dt)
            #pragma unroll
            for (int r = 0; r < 4; ++r)
                obuf[(rbase + lg * 4 + r) * 68 + dt * 16 + lc] = oacc[dt][r];
    }
    __syncthreads();
    if (cw == 0) {
        float inv[4];
        #pragma unroll
        for (int r = 0; r < 4; ++r) {
            int row = rbase + lg * 4 + r;
            inv[r] = 1.0f / (lred[row] + lred[32 + row]);
        }
        #pragma unroll
        for (int dt = 0; dt < 4; ++dt) {
            #pragma unroll
            for (int r = 0; r < 4; ++r) {
                int row = rbase + lg * 4 + r;
                float v = (oacc[dt][r] + obuf[row * 68 + dt * 16 + lc]) * inv[r];
                attn_out[((size_t)b * LL + q0 + row) * EE + h * DD + dt * 16 + lc] = f2bf(v);
            }
        }
    }
}

// ---------------- final FC via MFMA: out = X @ Wfc.T + bfc ----------------
__global__ __launch_bounds__(256) void fc_mfma_kernel(
    const u16* __restrict__ Xb, const u16* __restrict__ Wb,
    const float* __restrict__ bfc, float* __restrict__ out)
{
    __shared__ u16 As[128][72];
    __shared__ u16 Bs[128][72];
    int m0 = blockIdx.x * 128, n0 = blockIdx.y * 128;
    int t = threadIdx.x, lane = t & 63, w = t >> 6;
    int rw = w & 1, cw = w >> 1;
    int lg = lane >> 4, lc = lane & 15;
    f32x4 acc[4][4] = {};

    for (int kt = 0; kt < EE; kt += 64) {
        __syncthreads();
        #pragma unroll
        for (int i = 0; i < 4; ++i) {
            int unit = i * 256 + t;
            int row = unit >> 3, s = unit & 7;
            *(uint4*)&As[row][s * 8] = *(const uint4*)&Xb[(size_t)(m0 + row) * EE + kt + s * 8];
            *(uint4*)&Bs[row][s * 8] = *(const uint4*)&Wb[(size_t)(n0 + row) * EE + kt + s * 8];
        }
        __syncthreads();
        #pragma unroll
        for (int kc = 0; kc < 2; ++kc) {
            bf16x8 af[4], bf[4];
            #pragma unroll
            for (int i = 0; i < 4; ++i) {
                af[i] = *(const bf16x8*)&As[rw * 64 + i * 16 + lc][kc * 32 + lg * 8];
                bf[i] = *(const bf16x8*)&Bs[cw * 64 + i * 16 + lc][kc * 32 + lg * 8];
            }
            #pragma unroll
            for (int mi = 0; mi < 4; ++mi)
                #pragma unroll
                for (int ni = 0; ni < 4; ++ni)
                    acc[mi][ni] = MF(af[mi], bf[ni], acc[mi][ni]);
        }
    }
    #pragma unroll
    for (int mi = 0; mi < 4; ++mi) {
        #pragma unroll
        for (int ni = 0; ni < 4; ++ni) {
            int n = n0 + cw * 64 + ni * 16 + lc;
            float bias = bfc[n];
            #pragma unroll
            for (int r = 0; r < 4; ++r) {
                int m = m0 + rw * 64 + mi * 16 + lg * 4 + r;
                out[(size_t)m * EE + n] = acc[mi][ni][r] + bias;
            }
        }
    }
}

extern "C" void kernel_launch(void* const* d_in, const int* in_sizes, int n_in,
                              void* d_out, int out_size, void* d_ws, size_t ws_size,
                              hipStream_t stream) {
    const float* query = (const float*)d_in[0];
    const float* key   = (const float*)d_in[1];
    const float* value = (const float*)d_in[2];
    const int*   mask  = (const int*)d_in[3];
    const float* Wq  = (const float*)d_in[4];
    const float* bq  = (const float*)d_in[5];
    const float* Wk  = (const float*)d_in[6];
    const float* bk  = (const float*)d_in[7];
    const float* Wv  = (const float*)d_in[8];
    const float* bv  = (const float*)d_in[9];
    const float* Wfc = (const float*)d_in[10];
    const float* bfc = (const float*)d_in[11];
    const float* relk = (const float*)d_in[12];
    const float* relv = (const float*)d_in[13];
    float* out = (float*)d_out;

    char* ws = (char*)d_ws;
    u16* qb        = (u16*)(ws);                            // 4 MB
    u16* kb        = (u16*)(ws + (4u << 20));               // 4 MB
    u16* vtb       = (u16*)(ws + (8u << 20));               // 4 MB
    u16* attnb     = (u16*)(ws + (12u << 20));              // 4 MB
    u16* relk_pad  = (u16*)(ws + (16u << 20));              // 256 KB
    u16* relvt_pad = (u16*)(ws + (16u << 20) + 262144);     // 256 KB
    u16* wfcb      = (u16*)(ws + (16u << 20) + 524288);     // 512 KB

    proj_mfma_kernel<<<dim3(BB * HH, LL / 64), 256, 0, stream>>>(
        query, key, value, Wq, bq, Wk, bk, Wv, bv, qb, kb, vtb);
    prep_kernel<<<1024, 256, 0, stream>>>(relk, relv, Wfc, relk_pad, relvt_pad, wfcb);
    attn_mfma_kernel<<<dim3(BB * HH, LL / 32), 256, 0, stream>>>(
        qb, kb, vtb, mask, relk_pad, relvt_pad, attnb);
    fc_mfma_kernel<<<dim3(BB * LL / 128, EE / 128), 256, 0, stream>>>(attnb, wfcb, bfc, out);
}

// Round 10
// 109.527 us; speedup vs baseline: 1.4008x; 1.4008x over previous
//
#include <hip/hip_runtime.h>
#include <math.h>

#define BB 4
#define LL 1024
#define EE 512
#define HH 8
#define DD 64
#define MAXREL 512

typedef unsigned short u16;
typedef __attribute__((ext_vector_type(8))) short bf16x8;
typedef __attribute__((ext_vector_type(4))) float f32x4;

__device__ __forceinline__ u16 f2bf(float f) {
    unsigned int u = __float_as_uint(f);
    unsigned int r = (u + 0x7FFFu + ((u >> 16) & 1u)) >> 16;
    return (u16)r;
}
__device__ __forceinline__ float bf2f(u16 b) {
    return __uint_as_float(((unsigned int)b) << 16);
}
__device__ __forceinline__ bf16x8 ldf8_bf(const float* p) {
    const float4 a = *(const float4*)(p);
    const float4 b = *(const float4*)(p + 4);
    bf16x8 r;
    r[0] = (short)f2bf(a.x); r[1] = (short)f2bf(a.y);
    r[2] = (short)f2bf(a.z); r[3] = (short)f2bf(a.w);
    r[4] = (short)f2bf(b.x); r[5] = (short)f2bf(b.y);
    r[6] = (short)f2bf(b.z); r[7] = (short)f2bf(b.w);
    return r;
}

#define MF(A, B, C) __builtin_amdgcn_mfma_f32_16x16x32_bf16((A), (B), (C), 0, 0, 0)
// exp(x/8) = exp2(x * log2(e)/8)
#define EXPSC 0.1803368801111244f

// ---------------- projection via MFMA ----------------
__global__ __launch_bounds__(256) void proj_mfma_kernel(
    const float* __restrict__ q_in, const float* __restrict__ k_in, const float* __restrict__ v_in,
    const float* __restrict__ Wq, const float* __restrict__ bq,
    const float* __restrict__ Wk, const float* __restrict__ bk,
    const float* __restrict__ Wv, const float* __restrict__ bv,
    u16* __restrict__ qb, u16* __restrict__ kb, u16* __restrict__ vtb)
{
    int bh = blockIdx.x; int b = bh >> 3; int h = bh & 7;
    int l0 = blockIdx.y * 64;
    int t = threadIdx.x; int w = t >> 6; int lane = t & 63;
    int lg = lane >> 4, lc = lane & 15;
    int lt = l0 + w * 16;

    bf16x8 wq[4][2], wk[4][2], wv[4][2];
    #pragma unroll
    for (int dt = 0; dt < 4; ++dt)
        #pragma unroll
        for (int kc = 0; kc < 2; ++kc) {
            int d = dt * 16 + lc, ko = kc * 32 + lg * 8;
            wq[dt][kc] = ldf8_bf(Wq + d * DD + ko);
            wk[dt][kc] = ldf8_bf(Wk + d * DD + ko);
            wv[dt][kc] = ldf8_bf(Wv + d * DD + ko);
        }
    size_t xrow = ((size_t)b * LL + lt + lc) * EE + h * DD;
    bf16x8 xq[2], xk[2], xv[2];
    #pragma unroll
    for (int kc = 0; kc < 2; ++kc) {
        int ko = kc * 32 + lg * 8;
        xq[kc] = ldf8_bf(q_in + xrow + ko);
        xk[kc] = ldf8_bf(k_in + xrow + ko);
        xv[kc] = ldf8_bf(v_in + xrow + ko);
    }

    f32x4 aq[4] = {}, ak[4] = {}, av[4] = {};
    #pragma unroll
    for (int dt = 0; dt < 4; ++dt) {
        aq[dt] = MF(wq[dt][0], xq[0], aq[dt]);
        aq[dt] = MF(wq[dt][1], xq[1], aq[dt]);
        ak[dt] = MF(wk[dt][0], xk[0], ak[dt]);
        ak[dt] = MF(wk[dt][1], xk[1], ak[dt]);
        av[dt] = MF(xv[0], wv[dt][0], av[dt]);
        av[dt] = MF(xv[1], wv[dt][1], av[dt]);
    }

    #pragma unroll
    for (int dt = 0; dt < 4; ++dt) {
        u16 tq[4], tk[4], tv[4];
        #pragma unroll
        for (int r = 0; r < 4; ++r) {
            int d = dt * 16 + lg * 4 + r;
            tq[r] = f2bf(aq[dt][r] + bq[d]);
            tk[r] = f2bf(ak[dt][r] + bk[d]);
            tv[r] = f2bf(av[dt][r] + bv[dt * 16 + lc]);
        }
        size_t o = ((size_t)bh * LL + lt + lc) * DD + dt * 16 + lg * 4;
        *(uint2*)&qb[o] = *(uint2*)tq;
        *(uint2*)&kb[o] = *(uint2*)tk;
        size_t ov = ((size_t)bh * DD + dt * 16 + lc) * LL + lt + lg * 4;
        *(uint2*)&vtb[ov] = *(uint2*)tv;
    }
}

// ---------------- prep: padded bf16 rel tables + bf16 Wfc ----------------
__global__ __launch_bounds__(256) void prep_kernel(
    const float* __restrict__ relk, const float* __restrict__ relv, const float* __restrict__ Wfc,
    u16* __restrict__ relk_pad, u16* __restrict__ relvt_pad, u16* __restrict__ wfcb)
{
    int idx = blockIdx.x * 256 + threadIdx.x;   // 1024 blocks -> 262144
    if (idx < 2048 * DD) {
        int r = idx >> 6, d = idx & 63;
        int j = r - 512; j = j < 0 ? 0 : (j > 2 * MAXREL ? 2 * MAXREL : j);
        relk_pad[idx] = f2bf(relk[j * DD + d]);
        int dd = idx >> 11, c = idx & 2047;
        int j2 = c - 512; j2 = j2 < 0 ? 0 : (j2 > 2 * MAXREL ? 2 * MAXREL : j2);
        relvt_pad[idx] = f2bf(relv[j2 * DD + dd]);
    }
    if (idx < EE * EE) wfcb[idx] = f2bf(Wfc[idx]);
}

// ---------------- fused attention: softmax-behind pipeline ----------------
// grid (B*H, L/32), block 256 (4 waves). 2 barriers/chunk. Wave-local P.
// Iter c: scores+softmax of chunk c+1 (Ks double-buffered), PV of chunk c.
// The two MFMA chains are independent; softmax VALU overlaps PV drain.
__global__ __launch_bounds__(256) void attn_mfma_kernel(
    const u16* __restrict__ qb, const u16* __restrict__ kb, const u16* __restrict__ vtb,
    const int* __restrict__ mask,
    const u16* __restrict__ relk_pad, const u16* __restrict__ relvt_pad,
    u16* __restrict__ attn_out)
{
    __shared__ __align__(16) char smem[57600];
    // Ks0: 0..9216, Ks1: 9216..18432  [64][72] each
    u16* Vts  = (u16*)(smem + 18432);     // [64][72]   9216
    u16* RVts = (u16*)(smem + 27648);     // [64][120] 15360
    float* lred = (float*)(smem + 57344); // [64]
    float* obuf = (float*)smem;           // epilogue reuse [32][68]

    int bh = blockIdx.x, b = bh >> 3, h = bh & 7;
    int q0 = blockIdx.y * 32;
    int t = threadIdx.x, lane = t & 63, w = t >> 6;
    int rw = w & 1, cw = w >> 1;
    int rbase = rw * 16, c0a = cw * 32;
    int lg = lane >> 4, lc = lane & 15;
    int ub = c0a - rbase + 16;            // window base (0,16,32,48)
    size_t bhL = (size_t)bh * LL;
    const u16* kb_bh = kb + bhL * DD;
    const u16* vt_bh = vtb + (size_t)bh * DD * LL;
    const int* mk_b = mask + b * LL;
    u16* Pw  = (u16*)(smem + 43008) + w * 640;   // [16][40] per wave
    u16* Pqw = (u16*)(smem + 48128) + w * 1152;  // [16][72] per wave

    // staging index precompute
    int sr0 = t >> 3, ss0 = (t & 7) * 8;
    int sr1 = sr0 + 32;
    int rv_row = t >> 2, rv_q = (t & 3) * 24;
    const u16* rvg = relvt_pad + (size_t)rv_row * 2048 + rv_q;
    u16* rvl = RVts + rv_row * 120 + rv_q;
    const u16* rk_base = relk_pad + (size_t)(ub + lc) * DD + lg * 8;

    const u16* qrow = qb + (bhL + q0 + rbase + lc) * DD;
    bf16x8 qf0 = *(const bf16x8*)&qrow[lg * 8];
    bf16x8 qf1 = *(const bf16x8*)&qrow[32 + lg * 8];

    f32x4 s0, s1, g0, g1, g2;
    bf16x8 rk0, rk1, rk2, rk3, rk4, rk5;
    f32x4 oacc[4] = {};
    float lacc[4] = {0.f, 0.f, 0.f, 0.f};
    int delta0 = lc - lg * 4;

#define LOAD_RK(SB) do { \
    const u16* rkp_ = rk_base + (size_t)(SB) * DD; \
    rk0 = *(const bf16x8*)&rkp_[0]; \
    rk1 = *(const bf16x8*)&rkp_[32]; \
    rk2 = *(const bf16x8*)&rkp_[16 * DD]; \
    rk3 = *(const bf16x8*)&rkp_[16 * DD + 32]; \
    rk4 = *(const bf16x8*)&rkp_[32 * DD]; \
    rk5 = *(const bf16x8*)&rkp_[32 * DD + 32]; \
} while (0)

#define DO_SCORES(KBASE) do { \
    const u16* kp0_ = (KBASE) + (c0a + lc) * 72; \
    const u16* kp1_ = (KBASE) + (c0a + 16 + lc) * 72; \
    s0 = (f32x4){0.f,0.f,0.f,0.f}; s1 = s0; g0 = s0; g1 = s0; g2 = s0; \
    __builtin_amdgcn_s_setprio(1); \
    s0 = MF(qf0, *(const bf16x8*)&kp0_[lg * 8], s0); \
    s0 = MF(qf1, *(const bf16x8*)&kp0_[32 + lg * 8], s0); \
    s1 = MF(qf0, *(const bf16x8*)&kp1_[lg * 8], s1); \
    s1 = MF(qf1, *(const bf16x8*)&kp1_[32 + lg * 8], s1); \
    g0 = MF(qf0, rk0, g0); g0 = MF(qf1, rk1, g0); \
    g1 = MF(qf0, rk2, g1); g1 = MF(qf1, rk3, g1); \
    g2 = MF(qf0, rk4, g2); g2 = MF(qf1, rk5, g2); \
    __builtin_amdgcn_s_setprio(0); \
} while (0)

#define DO_SOFTMAX(MB0, MB1) do { \
    _Pragma("unroll") \
    for (int r = 0; r < 4; ++r) { \
        int d_ = delta0 - r; \
        int src_ = (lane & 48) | (d_ & 15); \
        float a0_ = __shfl(g0[r], src_, 64); \
        float a1_ = __shfl(g1[r], src_, 64); \
        float a2_ = __shfl(g2[r], src_, 64); \
        float gv0_ = (d_ >= 0) ? a1_ : a0_; \
        float gv1_ = (d_ >= 0) ? a2_ : a1_; \
        float p0_ = exp2f((s0[r] + (MB0) + gv0_) * EXPSC); \
        float p1_ = exp2f((s1[r] + (MB1) + gv1_) * EXPSC); \
        u16 pb0_ = f2bf(p0_), pb1_ = f2bf(p1_); \
        lacc[r] += p0_ + p1_; \
        int row_ = lg * 4 + r; \
        Pw[row_ * 40 + lc] = pb0_; \
        Pw[row_ * 40 + 16 + lc] = pb1_; \
        Pqw[row_ * 72 + lc - row_ + 16] = pb0_; \
        Pqw[row_ * 72 + 32 + lc - row_] = pb1_; \
    } \
} while (0)

    // ---- prolog ----
    #pragma unroll
    for (int i = 0; i < 3; ++i) {
        int u = lane + i * 64;
        if (u < 144) *(uint4*)&Pqw[u * 8] = make_uint4(0, 0, 0, 0);
    }
    if (t < 192) {
        int row = t / 3, j = t - row * 3;
        *(uint4*)&RVts[row * 120 + 96 + j * 8] = make_uint4(0, 0, 0, 0);
    }
    int sb0 = 992 - q0;
    {
        u16* Ks0 = (u16*)smem;
        u16* Ks1 = (u16*)(smem + 9216);
        *(uint4*)&Ks0[sr0 * 72 + ss0] = *(const uint4*)&kb_bh[(size_t)sr0 * DD + ss0];
        *(uint4*)&Ks0[sr1 * 72 + ss0] = *(const uint4*)&kb_bh[(size_t)sr1 * DD + ss0];
        *(uint4*)&Ks1[sr0 * 72 + ss0] = *(const uint4*)&kb_bh[(size_t)(64 + sr0) * DD + ss0];
        *(uint4*)&Ks1[sr1 * 72 + ss0] = *(const uint4*)&kb_bh[(size_t)(64 + sr1) * DD + ss0];
        *(uint4*)&Vts[sr0 * 72 + ss0] = *(const uint4*)&vt_bh[(size_t)sr0 * LL + ss0];
        *(uint4*)&Vts[sr1 * 72 + ss0] = *(const uint4*)&vt_bh[(size_t)sr1 * LL + ss0];
        *(uint4*)&rvl[0]  = *(const uint4*)&rvg[sb0];
        *(uint4*)&rvl[8]  = *(const uint4*)&rvg[sb0 + 8];
        *(uint4*)&rvl[16] = *(const uint4*)&rvg[sb0 + 16];
    }
    LOAD_RK(sb0);
    float mbp0 = (mk_b[c0a + lc] != 0) ? 0.f : -1e20f;
    float mbp1 = (mk_b[c0a + 16 + lc] != 0) ? 0.f : -1e20f;
    __syncthreads();
    DO_SCORES((const u16*)smem);     // chunk 0
    LOAD_RK(sb0 + 64);               // rel-K(1)
    DO_SOFTMAX(mbp0, mbp1);          // P(0)

    // ---- main loop: iter c does scores/softmax(c+1) + PV(c) ----
    #pragma unroll 1
    for (int c = 0; c < 16; ++c) {
        int k0 = c * 64;
        int sb_ = k0 - q0 + 992;
        uint4 rK0, rK1, rV0, rV1;
        float mbn0 = 0.f, mbn1 = 0.f;
        if (c < 14) {
            rK0 = *(const uint4*)&kb_bh[(size_t)(k0 + 128 + sr0) * DD + ss0];
            rK1 = *(const uint4*)&kb_bh[(size_t)(k0 + 128 + sr1) * DD + ss0];
        }
        if (c < 15) {
            int k0n = k0 + 64;
            rV0 = *(const uint4*)&vt_bh[(size_t)sr0 * LL + k0n + ss0];
            rV1 = *(const uint4*)&vt_bh[(size_t)sr1 * LL + k0n + ss0];
            mbn0 = (mk_b[k0n + c0a + lc] != 0) ? 0.f : -1e20f;
            mbn1 = (mk_b[k0n + c0a + 16 + lc] != 0) ? 0.f : -1e20f;
        }

        // P(c) fragments (written last iteration / prolog; wave-local, program order)
        bf16x8 pa  = *(const bf16x8*)&Pw[lc * 40 + lg * 8];
        bf16x8 pq0 = *(const bf16x8*)&Pqw[lc * 72 + lg * 8];
        bf16x8 pq1 = *(const bf16x8*)&Pqw[lc * 72 + 32 + lg * 8];

        if (c < 15) {
            const u16* kcur = (const u16*)(smem + ((c + 1) & 1) * 9216);
            DO_SCORES(kcur);                   // chunk c+1
            if (c < 14) LOAD_RK(sb_ + 128);    // rel-K(c+2)
        }

        // PV(c) — independent of scores(c+1)
        __builtin_amdgcn_s_setprio(1);
        #pragma unroll
        for (int dt = 0; dt < 4; ++dt) {
            const u16* vp = &Vts[(dt * 16 + lc) * 72 + c0a];
            const u16* rp = &RVts[(dt * 16 + lc) * 120 + ub];
            oacc[dt] = MF(pa,  *(const bf16x8*)&vp[lg * 8], oacc[dt]);
            oacc[dt] = MF(pq0, *(const bf16x8*)&rp[lg * 8], oacc[dt]);
            oacc[dt] = MF(pq1, *(const bf16x8*)&rp[32 + lg * 8], oacc[dt]);
        }
        __builtin_amdgcn_s_setprio(0);

        if (c < 15) {
            DO_SOFTMAX(mbn0, mbn1);            // P(c+1), overlaps PV drain
            int sbn = sb_ + 64;
            uint4 bb0 = *(const uint4*)&rvg[sbn];
            uint4 bb1 = *(const uint4*)&rvg[sbn + 8];
            uint4 bb2 = *(const uint4*)&rvg[sbn + 16];
            __syncthreads();                   // all waves done reading chunk c tiles
            if (c < 14) {
                u16* kwr = (u16*)(smem + (c & 1) * 9216);
                *(uint4*)&kwr[sr0 * 72 + ss0] = rK0;
                *(uint4*)&kwr[sr1 * 72 + ss0] = rK1;
            }
            *(uint4*)&Vts[sr0 * 72 + ss0] = rV0;
            *(uint4*)&Vts[sr1 * 72 + ss0] = rV1;
            *(uint4*)&rvl[0]  = bb0;
            *(uint4*)&rvl[8]  = bb1;
            *(uint4*)&rvl[16] = bb2;
            __syncthreads();                   // chunk c+1 tiles visible
        }
    }
#undef LOAD_RK
#undef DO_SCORES
#undef DO_SOFTMAX

    // ---- epilogue: row-sum + cw-pair combine ----
    #pragma unroll
    for (int m2 = 1; m2 <= 8; m2 <<= 1) {
        #pragma unroll
        for (int r = 0; r < 4; ++r) lacc[r] += __shfl_xor(lacc[r], m2);
    }
    __syncthreads();
    if (lc == 0) {
        #pragma unroll
        for (int r = 0; r < 4; ++r) lred[cw * 32 + rbase + lg * 4 + r] = lacc[r];
    }
    __syncthreads();
    if (cw == 1) {
        #pragma unroll
        for (int dt = 0; dt < 4; ++dt)
            #pragma unroll
            for (int r = 0; r < 4; ++r)
                obuf[(rbase + lg * 4 + r) * 68 + dt * 16 + lc] = oacc[dt][r];
    }
    __syncthreads();
    if (cw == 0) {
        float inv[4];
        #pragma unroll
        for (int r = 0; r < 4; ++r) {
            int row = rbase + lg * 4 + r;
            inv[r] = 1.0f / (lred[row] + lred[32 + row]);
        }
        #pragma unroll
        for (int dt = 0; dt < 4; ++dt) {
            #pragma unroll
            for (int r = 0; r < 4; ++r) {
                int row = rbase + lg * 4 + r;
                float v = (oacc[dt][r] + obuf[row * 68 + dt * 16 + lc]) * inv[r];
                attn_out[((size_t)b * LL + q0 + row) * EE + h * DD + dt * 16 + lc] = f2bf(v);
            }
        }
    }
}

// ---------------- final FC via MFMA: out = X @ Wfc.T + bfc ----------------
__global__ __launch_bounds__(256) void fc_mfma_kernel(
    const u16* __restrict__ Xb, const u16* __restrict__ Wb,
    const float* __restrict__ bfc, float* __restrict__ out)
{
    __shared__ u16 As[128][72];
    __shared__ u16 Bs[128][72];
    int m0 = blockIdx.x * 128, n0 = blockIdx.y * 128;
    int t = threadIdx.x, lane = t & 63, w = t >> 6;
    int rw = w & 1, cw = w >> 1;
    int lg = lane >> 4, lc = lane & 15;
    f32x4 acc[4][4] = {};

    for (int kt = 0; kt < EE; kt += 64) {
        __syncthreads();
        #pragma unroll
        for (int i = 0; i < 4; ++i) {
            int unit = i * 256 + t;
            int row = unit >> 3, s = unit & 7;
            *(uint4*)&As[row][s * 8] = *(const uint4*)&Xb[(size_t)(m0 + row) * EE + kt + s * 8];
            *(uint4*)&Bs[row][s * 8] = *(const uint4*)&Wb[(size_t)(n0 + row) * EE + kt + s * 8];
        }
        __syncthreads();
        #pragma unroll
        for (int kc = 0; kc < 2; ++kc) {
            bf16x8 af[4], bf[4];
            #pragma unroll
            for (int i = 0; i < 4; ++i) {
                af[i] = *(const bf16x8*)&As[rw * 64 + i * 16 + lc][kc * 32 + lg * 8];
                bf[i] = *(const bf16x8*)&Bs[cw * 64 + i * 16 + lc][kc * 32 + lg * 8];
            }
            #pragma unroll
            for (int mi = 0; mi < 4; ++mi)
                #pragma unroll
                for (int ni = 0; ni < 4; ++ni)
                    acc[mi][ni] = MF(af[mi], bf[ni], acc[mi][ni]);
        }
    }
    #pragma unroll
    for (int mi = 0; mi < 4; ++mi) {
        #pragma unroll
        for (int ni = 0; ni < 4; ++ni) {
            int n = n0 + cw * 64 + ni * 16 + lc;
            float bias = bfc[n];
            #pragma unroll
            for (int r = 0; r < 4; ++r) {
                int m = m0 + rw * 64 + mi * 16 + lg * 4 + r;
                out[(size_t)m * EE + n] = acc[mi][ni][r] + bias;
            }
        }
    }
}

extern "C" void kernel_launch(void* const* d_in, const int* in_sizes, int n_in,
                              void* d_out, int out_size, void* d_ws, size_t ws_size,
                              hipStream_t stream) {
    const float* query = (const float*)d_in[0];
    const float* key   = (const float*)d_in[1];
    const float* value = (const float*)d_in[2];
    const int*   mask  = (const int*)d_in[3];
    const float* Wq  = (const float*)d_in[4];
    const float* bq  = (const float*)d_in[5];
    const float* Wk  = (const float*)d_in[6];
    const float* bk  = (const float*)d_in[7];
    const float* Wv  = (const float*)d_in[8];
    const float* bv  = (const float*)d_in[9];
    const float* Wfc = (const float*)d_in[10];
    const float* bfc = (const float*)d_in[11];
    const float* relk = (const float*)d_in[12];
    const float* relv = (const float*)d_in[13];
    float* out = (float*)d_out;

    char* ws = (char*)d_ws;
    u16* qb        = (u16*)(ws);                            // 4 MB
    u16* kb        = (u16*)(ws + (4u << 20));               // 4 MB
    u16* vtb       = (u16*)(ws + (8u << 20));               // 4 MB
    u16* attnb     = (u16*)(ws + (12u << 20));              // 4 MB
    u16* relk_pad  = (u16*)(ws + (16u << 20));              // 256 KB
    u16* relvt_pad = (u16*)(ws + (16u << 20) + 262144);     // 256 KB
    u16* wfcb      = (u16*)(ws + (16u << 20) + 524288);     // 512 KB

    proj_mfma_kernel<<<dim3(BB * HH, LL / 64), 256, 0, stream>>>(
        query, key, value, Wq, bq, Wk, bk, Wv, bv, qb, kb, vtb);
    prep_kernel<<<1024, 256, 0, stream>>>(relk, relv, Wfc, relk_pad, relvt_pad, wfcb);
    attn_mfma_kernel<<<dim3(BB * HH, LL / 32), 256, 0, stream>>>(
        qb, kb, vtb, mask, relk_pad, relvt_pad, attnb);
    fc_mfma_kernel<<<dim3(BB * LL / 128, EE / 128), 256, 0, stream>>>(attnb, wfcb, bfc, out);
}